// Round 5
// baseline (169.715 us; speedup 1.0000x reference)
//
#include <hip/hip_runtime.h>

#define FILLV (-10000.0f)

typedef __attribute__((ext_vector_type(4))) float f32x4;

__device__ __forceinline__ f32x4 vmax4(f32x4 a, f32x4 b) {
    f32x4 r;
    r.x = fmaxf(a.x, b.x);
    r.y = fmaxf(a.y, b.y);
    r.z = fmaxf(a.z, b.z);
    r.w = fmaxf(a.w, b.w);
    return r;
}

__device__ __forceinline__ f32x4 ntload(const f32x4* p) {
    return __builtin_nontemporal_load(p);
}

__device__ __forceinline__ f32x4 fillv4() {
    f32x4 v = {FILLV, FILLV, FILLV, FILLV};
    return v;
}

// Monotone order-preserving encoding: max over encoded u32 == max over float.
// (No NaNs in the data; FILL sentinel and normals only.)
__device__ __forceinline__ unsigned enc_f32(float f) {
    unsigned x = __float_as_uint(f);
    return (x & 0x80000000u) ? ~x : (x | 0x80000000u);
}
__device__ __forceinline__ float dec_f32(unsigned u) {
    unsigned x = (u & 0x80000000u) ? (u ^ 0x80000000u) : ~u;
    return __uint_as_float(x);
}

// ---------------------------------------------------------------------------
// Kernel 0: init the encoded accumulator to enc(FILL). Runs every call
// (ws is not re-poisoned between replays; this IS the per-call reset).
// ---------------------------------------------------------------------------
__global__ void feasel_init_kernel(unsigned* __restrict__ acc, int n) {
    int i = blockIdx.x * blockDim.x + threadIdx.x;
    if (i < n) acc[i] = enc_f32(FILLV);
}

// ---------------------------------------------------------------------------
// Kernel 1: self-scheduled balanced masked max, merged via atomicMax.
// Each block rebuilds the (b, seg)-item prefix map from `lengths` (no
// cross-kernel handoff), grid-strides items; per item reduces seg rows in
// registers then does 4 u32 atomicMax per thread into acc[b*D + col].
// ---------------------------------------------------------------------------
__global__ __launch_bounds__(256, 4)
void feasel_main_kernel(const float* __restrict__ feat,
                        const int* __restrict__ lengths,
                        unsigned* __restrict__ acc,
                        int B, int L, int DV, int seg) {
    __shared__ int off[1025];            // prefix offsets, supports B <= 1024
    const int t = threadIdx.x;

    for (int b = t; b < B; b += blockDim.x) {
        int len = lengths[b];
        len = len < 0 ? 0 : (len > L ? L : len);
        off[b + 1] = (len + seg - 1) / seg;
    }
    __syncthreads();
    if (t == 0) {
        off[0] = 0;
        for (int b = 0; b < B; ++b) off[b + 1] += off[b];
    }
    __syncthreads();
    const int W = off[B];

    for (int i = blockIdx.x; i < W; i += gridDim.x) {
        int lo = 0, hi = B;
        while (hi - lo > 1) {
            int m = (lo + hi) >> 1;
            if (off[m] <= i) lo = m; else hi = m;
        }
        const int b = lo;
        const int s = i - off[lo];

        int len = lengths[b];
        len = len > L ? L : len;
        const int l0 = s * seg;
        const int l1 = min(l0 + seg, len);

        const f32x4* __restrict__ p =
            reinterpret_cast<const f32x4*>(feat) + (size_t)b * L * DV + (size_t)l0 * DV + t;

        f32x4 a0 = fillv4(), a1 = fillv4(), a2 = fillv4(), a3 = fillv4();

        int l = l0;
        for (; l + 8 <= l1; l += 8) {
            f32x4 v0 = ntload(p + 0 * (size_t)DV);
            f32x4 v1 = ntload(p + 1 * (size_t)DV);
            f32x4 v2 = ntload(p + 2 * (size_t)DV);
            f32x4 v3 = ntload(p + 3 * (size_t)DV);
            f32x4 v4 = ntload(p + 4 * (size_t)DV);
            f32x4 v5 = ntload(p + 5 * (size_t)DV);
            f32x4 v6 = ntload(p + 6 * (size_t)DV);
            f32x4 v7 = ntload(p + 7 * (size_t)DV);
            a0 = vmax4(a0, vmax4(v0, v4));
            a1 = vmax4(a1, vmax4(v1, v5));
            a2 = vmax4(a2, vmax4(v2, v6));
            a3 = vmax4(a3, vmax4(v3, v7));
            p += 8 * (size_t)DV;
        }
        for (; l < l1; ++l) {
            a0 = vmax4(a0, ntload(p));
            p += DV;
        }
        a0 = vmax4(vmax4(a0, a1), vmax4(a2, a3));

        unsigned* dst = acc + ((size_t)b * DV + t) * 4;
        atomicMax(dst + 0, enc_f32(a0.x));
        atomicMax(dst + 1, enc_f32(a0.y));
        atomicMax(dst + 2, enc_f32(a0.z));
        atomicMax(dst + 3, enc_f32(a0.w));
    }
}

// ---------------------------------------------------------------------------
// Kernel 2: decode + len==0 -> 0, write out. Tiny (B*D elements).
// ---------------------------------------------------------------------------
__global__ void feasel_decode_kernel(const unsigned* __restrict__ acc,
                                     const int* __restrict__ lengths,
                                     float* __restrict__ out,
                                     int D, int n) {
    int i = blockIdx.x * blockDim.x + threadIdx.x;
    if (i >= n) return;
    const int b = i / D;
    float f = dec_f32(acc[i]);
    if (lengths[b] <= 0) f = 0.f;
    out[i] = f;
}

// ---------------------------------------------------------------------------
// Fallback (tiny ws or B > 1024): one block per batch, direct reduction.
// ---------------------------------------------------------------------------
__global__ void feasel_direct_kernel(const float* __restrict__ feat,
                                     const int* __restrict__ lengths,
                                     float* __restrict__ out,
                                     int L, int DV) {
    const int b = blockIdx.x;
    const int t = threadIdx.x;
    int len = lengths[b];
    len = len < 0 ? 0 : (len > L ? L : len);

    const f32x4* __restrict__ p =
        reinterpret_cast<const f32x4*>(feat) + (size_t)b * L * DV + t;

    f32x4 a0 = fillv4(), a1 = fillv4(), a2 = fillv4(), a3 = fillv4();
    int l = 0;
    for (; l + 4 <= len; l += 4) {
        a0 = vmax4(a0, ntload(p + 0 * (size_t)DV));
        a1 = vmax4(a1, ntload(p + 1 * (size_t)DV));
        a2 = vmax4(a2, ntload(p + 2 * (size_t)DV));
        a3 = vmax4(a3, ntload(p + 3 * (size_t)DV));
        p += 4 * (size_t)DV;
    }
    for (; l < len; ++l) {
        a0 = vmax4(a0, ntload(p));
        p += DV;
    }
    a0 = vmax4(vmax4(a0, a1), vmax4(a2, a3));
    if (len <= 0) {
        f32x4 z = {0.f, 0.f, 0.f, 0.f};
        a0 = z;
    }
    reinterpret_cast<f32x4*>(out)[(size_t)b * DV + t] = a0;
}

extern "C" void kernel_launch(void* const* d_in, const int* in_sizes, int n_in,
                              void* d_out, int out_size, void* d_ws, size_t ws_size,
                              hipStream_t stream) {
    const float* feat    = (const float*)d_in[0];   // [B, L, D] fp32
    const int*   lengths = (const int*)d_in[1];     // [B] int32
    float*       out     = (float*)d_out;           // [B, D] fp32

    const int B  = in_sizes[1];
    const int D  = out_size / B;                    // 1024
    const int DV = D / 4;                           // 256 float4 per row
    const int L  = in_sizes[0] / (B * D);           // 4096
    const int N  = B * D;                           // 65536 accumulator slots

    if ((size_t)N * sizeof(unsigned) <= ws_size && B <= 1024) {
        unsigned* acc = (unsigned*)d_ws;
        const int seg = 16;                         // 64 KB items; W ~ 8.2K

        feasel_init_kernel<<<(N + 255) / 256, 256, 0, stream>>>(acc, N);

        feasel_main_kernel<<<1024, 256, 0, stream>>>(feat, lengths, acc,
                                                     B, L, DV, seg);

        feasel_decode_kernel<<<(N + 255) / 256, 256, 0, stream>>>(acc, lengths, out, D, N);
    } else {
        feasel_direct_kernel<<<B, DV, 0, stream>>>(feat, lengths, out, L, DV);
    }
}

// Round 6
// 107.833 us; speedup vs baseline: 1.5739x; 1.5739x over previous
//
#include <hip/hip_runtime.h>

#define FILLV (-10000.0f)

typedef __attribute__((ext_vector_type(4))) float f32x4;

__device__ __forceinline__ f32x4 vmax4(f32x4 a, f32x4 b) {
    f32x4 r;
    r.x = fmaxf(a.x, b.x);
    r.y = fmaxf(a.y, b.y);
    r.z = fmaxf(a.z, b.z);
    r.w = fmaxf(a.w, b.w);
    return r;
}

__device__ __forceinline__ f32x4 ntload(const f32x4* p) {
    return __builtin_nontemporal_load(p);
}

__device__ __forceinline__ f32x4 fillv4() {
    f32x4 v = {FILLV, FILLV, FILLV, FILLV};
    return v;
}

// ---------------------------------------------------------------------------
// Kernel 1: self-scheduled balanced partial max (two-pass structure, R4).
// Fixed grid; each block rebuilds the (b, seg)-item prefix map from `lengths`
// (no cross-kernel handoff), takes a CONTIGUOUS equal slice of the item list,
// reduces each item (seg rows) in registers, writes partial slot (b,s).
// unroll-4 keeps VGPR <= 64 so __launch_bounds__(256,8) gives 8 blocks/CU
// (32 waves/CU) for DRAM latency hiding.
// ---------------------------------------------------------------------------
__global__ __launch_bounds__(256, 8)
void feasel_partial_kernel(const float* __restrict__ feat,
                           const int* __restrict__ lengths,
                           float* __restrict__ part,
                           int B, int L, int DV, int seg, int S) {
    __shared__ int off[1025];            // prefix offsets, supports B <= 1024
    const int t = threadIdx.x;

    for (int b = t; b < B; b += blockDim.x) {
        int len = lengths[b];
        len = len < 0 ? 0 : (len > L ? L : len);
        int n = (len + seg - 1) / seg;
        if (n > S) n = S;
        off[b + 1] = n;
    }
    __syncthreads();
    if (t == 0) {
        off[0] = 0;
        for (int b = 0; b < B; ++b) off[b + 1] += off[b];
    }
    __syncthreads();
    const unsigned W = (unsigned)off[B];

    // contiguous equal split of [0, W) across the grid
    const unsigned G  = gridDim.x;
    const unsigned i0 = (unsigned)(((unsigned long long)W * blockIdx.x) / G);
    const unsigned i1 = (unsigned)(((unsigned long long)W * (blockIdx.x + 1)) / G);

    for (unsigned i = i0; i < i1; ++i) {
        // largest b with off[b] <= i
        int lo = 0, hi = B;
        while (hi - lo > 1) {
            int m = (lo + hi) >> 1;
            if (off[m] <= (int)i) lo = m; else hi = m;
        }
        const int b = lo;
        const int s = (int)i - off[lo];

        int len = lengths[b];
        len = len > L ? L : len;
        const int l0 = s * seg;
        const int l1 = min(l0 + seg, len);

        const f32x4* __restrict__ p =
            reinterpret_cast<const f32x4*>(feat) + (size_t)b * L * DV + (size_t)l0 * DV + t;

        f32x4 a0 = fillv4(), a1 = fillv4(), a2 = fillv4(), a3 = fillv4();

        int l = l0;
        for (; l + 4 <= l1; l += 4) {
            f32x4 v0 = ntload(p + 0 * (size_t)DV);
            f32x4 v1 = ntload(p + 1 * (size_t)DV);
            f32x4 v2 = ntload(p + 2 * (size_t)DV);
            f32x4 v3 = ntload(p + 3 * (size_t)DV);
            a0 = vmax4(a0, v0);
            a1 = vmax4(a1, v1);
            a2 = vmax4(a2, v2);
            a3 = vmax4(a3, v3);
            p += 4 * (size_t)DV;
        }
        for (; l < l1; ++l) {
            a0 = vmax4(a0, ntload(p));
            p += DV;
        }
        a0 = vmax4(vmax4(a0, a1), vmax4(a2, a3));

        reinterpret_cast<f32x4*>(part)[((size_t)b * S + s) * DV + t] = a0;
    }
}

// ---------------------------------------------------------------------------
// Kernel 2: reduce the valid segments per batch; len==0 -> 0.
// Grid (B, DV/64) x 64 threads. Reads only slots kernel1 wrote this call
// (s < nseg, same formula from the same `lengths`).
// ---------------------------------------------------------------------------
__global__ void feasel_reduce_kernel(const float* __restrict__ part,
                                     const int* __restrict__ lengths,
                                     float* __restrict__ out,
                                     int L, int DV, int seg, int S) {
    const int b = blockIdx.x;
    const int c = blockIdx.y * 64 + threadIdx.x;
    if (c >= DV) return;

    int len = lengths[b];
    len = len < 0 ? 0 : (len > L ? L : len);
    int nseg = (len + seg - 1) / seg;
    if (nseg > S) nseg = S;

    f32x4 acc;
    if (len <= 0) {
        f32x4 z = {0.f, 0.f, 0.f, 0.f};
        acc = z;
    } else {
        const f32x4* __restrict__ p =
            reinterpret_cast<const f32x4*>(part) + (size_t)b * S * DV + c;
        f32x4 a0 = fillv4(), a1 = fillv4(), a2 = fillv4(), a3 = fillv4();
        int s = 0;
        for (; s + 4 <= nseg; s += 4) {
            a0 = vmax4(a0, p[(size_t)(s + 0) * DV]);
            a1 = vmax4(a1, p[(size_t)(s + 1) * DV]);
            a2 = vmax4(a2, p[(size_t)(s + 2) * DV]);
            a3 = vmax4(a3, p[(size_t)(s + 3) * DV]);
        }
        for (; s < nseg; ++s)
            a0 = vmax4(a0, p[(size_t)s * DV]);
        acc = vmax4(vmax4(a0, a1), vmax4(a2, a3));
    }
    reinterpret_cast<f32x4*>(out)[(size_t)b * DV + c] = acc;
}

// ---------------------------------------------------------------------------
// Fallback (tiny ws or B > 1024): one block per batch, direct reduction.
// ---------------------------------------------------------------------------
__global__ void feasel_direct_kernel(const float* __restrict__ feat,
                                     const int* __restrict__ lengths,
                                     float* __restrict__ out,
                                     int L, int DV) {
    const int b = blockIdx.x;
    const int t = threadIdx.x;
    int len = lengths[b];
    len = len < 0 ? 0 : (len > L ? L : len);

    const f32x4* __restrict__ p =
        reinterpret_cast<const f32x4*>(feat) + (size_t)b * L * DV + t;

    f32x4 a0 = fillv4(), a1 = fillv4(), a2 = fillv4(), a3 = fillv4();
    int l = 0;
    for (; l + 4 <= len; l += 4) {
        a0 = vmax4(a0, ntload(p + 0 * (size_t)DV));
        a1 = vmax4(a1, ntload(p + 1 * (size_t)DV));
        a2 = vmax4(a2, ntload(p + 2 * (size_t)DV));
        a3 = vmax4(a3, ntload(p + 3 * (size_t)DV));
        p += 4 * (size_t)DV;
    }
    for (; l < len; ++l) {
        a0 = vmax4(a0, ntload(p));
        p += DV;
    }
    a0 = vmax4(vmax4(a0, a1), vmax4(a2, a3));
    if (len <= 0) {
        f32x4 z = {0.f, 0.f, 0.f, 0.f};
        a0 = z;
    }
    reinterpret_cast<f32x4*>(out)[(size_t)b * DV + t] = a0;
}

extern "C" void kernel_launch(void* const* d_in, const int* in_sizes, int n_in,
                              void* d_out, int out_size, void* d_ws, size_t ws_size,
                              hipStream_t stream) {
    const float* feat    = (const float*)d_in[0];   // [B, L, D] fp32
    const int*   lengths = (const int*)d_in[1];     // [B] int32
    float*       out     = (float*)d_out;           // [B, D] fp32

    const int B  = in_sizes[1];
    const int D  = out_size / B;                    // 1024
    const int DV = D / 4;                           // 256 float4 per row
    const int L  = in_sizes[0] / (B * D);           // 4096

    // Segments per batch: largest power of two <= 128 whose partial buffer fits ws.
    int S = 128;
    while (S > 1 && (size_t)B * S * D * sizeof(float) > ws_size) S >>= 1;

    if ((size_t)B * S * D * sizeof(float) <= ws_size && B <= 1024) {
        float* part   = (float*)d_ws;
        const int seg = (L + S - 1) / S;

        feasel_partial_kernel<<<2048, 256, 0, stream>>>(feat, lengths, part,
                                                        B, L, DV, seg, S);

        dim3 grid2(B, (DV + 63) / 64);
        feasel_reduce_kernel<<<grid2, 64, 0, stream>>>(part, lengths, out, L, DV, seg, S);
    } else {
        feasel_direct_kernel<<<B, DV, 0, stream>>>(feat, lengths, out, L, DV);
    }
}